// Round 5
// baseline (7663.324 us; speedup 1.0000x reference)
//
#include <hip/hip_runtime.h>
#include <hip/hip_bf16.h>

#define S_N 50000
#define E_N 400000
#define FD 128
#define FM 256
#define FM2 1280
#define CH 40000      // MLP1 chunk rows (625 * 64), 10 chunks
#define NC 10
#define RCH 10000     // MLP2 row chunk, 5 chunks

// jnp.nan_to_num
__device__ __forceinline__ float n2n(float x) {
  if (x != x) return 0.0f;
  const float M = 3.402823466e38f;
  if (x > M) return M;
  if (x < -M) return -M;
  return x;
}

// ---------------------------------------------------------------------------
// Probe index dtype. flags[1] = 1 if int64 edge_index.
// ---------------------------------------------------------------------------
__global__ void probe_kernel(const void* __restrict__ eidx_raw, int* __restrict__ flags)
{
  if (threadIdx.x != 0 || blockIdx.x != 0) return;
  const long long* e64 = (const long long*)eidx_raw;
  int ok64 = 1;
  for (int i = 0; i < 64; ++i) {
    long long v = e64[i];
    if (v < 0 || v >= S_N) { ok64 = 0; break; }
  }
  flags[1] = ok64;
}

__global__ __launch_bounds__(256) void idx_kernel(
    const void* __restrict__ eidx, int* __restrict__ src32,
    int* __restrict__ tgt32, const int* __restrict__ flags)
{
  const int e = blockIdx.x * 256 + threadIdx.x;
  if (e >= E_N) return;
  if (flags[1]) {
    const long long* p = (const long long*)eidx;
    src32[e] = (int)p[e];
    tgt32[e] = (int)p[E_N + e];
  } else {
    const int* p = (const int*)eidx;
    src32[e] = p[e];
    tgt32[e] = p[E_N + e];
  }
}

// ---------------------------------------------------------------------------
// GEMM1 (f32): out = leaky(concat(x_t[tgt_c], ea_c) @ W1a^T + b, 0.1)
// Chunk-local pointers; rows exact multiples of 64.
// ---------------------------------------------------------------------------
__global__ __launch_bounds__(256) void gemm1_f32_kernel(
    const float* __restrict__ x_t, const float* __restrict__ ea_c,
    const int* __restrict__ tgt_c, const float* __restrict__ W,
    const float* __restrict__ bias, float* __restrict__ out)
{
  __shared__ float As[16][68];
  __shared__ float Bs[16][68];
  __shared__ int s_tgt[64];
  const int t = threadIdx.x;
  const int by = blockIdx.x, bx = blockIdx.y;
  const int row0 = by * 64;
  if (t < 64) s_tgt[t] = tgt_c[row0 + t];
  __syncthreads();
  const int lr  = t >> 2;
  const int lk4 = (t & 3) * 4;
  const int erow = row0 + lr;
  const int grow = s_tgt[lr];
  const int wrow = bx * 64 + lr;
  const int tx = t & 15, ty = t >> 4;
  float acc[4][4] = {};
  for (int kt = 0; kt < FM; kt += 16) {
    const int k0 = kt + lk4;
    const float* ap = (k0 < FD) ? (x_t + (size_t)grow * FD + k0)
                                : (ea_c + (size_t)erow * FD + (k0 - FD));
    const float4 av = *(const float4*)ap;
    As[lk4 + 0][lr] = av.x; As[lk4 + 1][lr] = av.y;
    As[lk4 + 2][lr] = av.z; As[lk4 + 3][lr] = av.w;
    const float4 wv = *(const float4*)(W + (size_t)wrow * FM + k0);
    Bs[lk4 + 0][lr] = wv.x; Bs[lk4 + 1][lr] = wv.y;
    Bs[lk4 + 2][lr] = wv.z; Bs[lk4 + 3][lr] = wv.w;
    __syncthreads();
#pragma unroll
    for (int kk = 0; kk < 16; ++kk) {
      float a[4], b[4];
#pragma unroll
      for (int i = 0; i < 4; ++i) a[i] = As[kk][ty * 4 + i];
#pragma unroll
      for (int j = 0; j < 4; ++j) b[j] = Bs[kk][tx * 4 + j];
#pragma unroll
      for (int i = 0; i < 4; ++i)
#pragma unroll
        for (int j = 0; j < 4; ++j) acc[i][j] += a[i] * b[j];
    }
    __syncthreads();
  }
#pragma unroll
  for (int i = 0; i < 4; ++i) {
    const size_t r = (size_t)(row0 + ty * 4 + i);
#pragma unroll
    for (int j = 0; j < 4; ++j) {
      const int c = bx * 64 + tx * 4 + j;
      float v = acc[i][j] + bias[c];
      v = v > 0.0f ? v : 0.1f * v;
      out[r * FM + c] = v;
    }
  }
}

// ---------------------------------------------------------------------------
// Generic f32 GEMM: out[M,N] = act( A[M,K] @ W[N,K]^T + bias[N] )
// ---------------------------------------------------------------------------
template <bool LEAKY>
__global__ __launch_bounds__(256) void gemm_f32_kernel(
    const float* __restrict__ A, const float* __restrict__ W,
    const float* __restrict__ bias, float* __restrict__ out,
    int M, int N, int K)
{
  __shared__ float As[16][68];
  __shared__ float Bs[16][68];
  const int t = threadIdx.x;
  const int by = blockIdx.x, bx = blockIdx.y;
  const int row0 = by * 64;
  const int lr  = t >> 2;
  const int lk4 = (t & 3) * 4;
  const int arow = row0 + lr;
  const int wrow = bx * 64 + lr;
  const int tx = t & 15, ty = t >> 4;
  float acc[4][4] = {};
  for (int kt = 0; kt < K; kt += 16) {
    const int k0 = kt + lk4;
    if (arow < M) {
      const float4 av = *(const float4*)(A + (size_t)arow * K + k0);
      As[lk4 + 0][lr] = av.x; As[lk4 + 1][lr] = av.y;
      As[lk4 + 2][lr] = av.z; As[lk4 + 3][lr] = av.w;
    } else {
      As[lk4 + 0][lr] = 0.f; As[lk4 + 1][lr] = 0.f;
      As[lk4 + 2][lr] = 0.f; As[lk4 + 3][lr] = 0.f;
    }
    const float4 wv = *(const float4*)(W + (size_t)wrow * K + k0);
    Bs[lk4 + 0][lr] = wv.x; Bs[lk4 + 1][lr] = wv.y;
    Bs[lk4 + 2][lr] = wv.z; Bs[lk4 + 3][lr] = wv.w;
    __syncthreads();
#pragma unroll
    for (int kk = 0; kk < 16; ++kk) {
      float a[4], b[4];
#pragma unroll
      for (int i = 0; i < 4; ++i) a[i] = As[kk][ty * 4 + i];
#pragma unroll
      for (int j = 0; j < 4; ++j) b[j] = Bs[kk][tx * 4 + j];
#pragma unroll
      for (int i = 0; i < 4; ++i)
#pragma unroll
        for (int j = 0; j < 4; ++j) acc[i][j] += a[i] * b[j];
    }
    __syncthreads();
  }
#pragma unroll
  for (int i = 0; i < 4; ++i) {
    const int r = row0 + ty * 4 + i;
    if (r < M) {
#pragma unroll
      for (int j = 0; j < 4; ++j) {
        const int c = bx * 64 + tx * 4 + j;
        float v = acc[i][j] + bias[c];
        if (LEAKY) v = v > 0.0f ? v : 0.1f * v;
        out[(size_t)r * N + c] = v;
      }
    }
  }
}

// ---------------------------------------------------------------------------
// Stats embedded in h [S,1280] f32: cols [0:128)=x_s, [128:384)=mean,
// [384:640)=std, [640:896)=skew, [896:1152)=kurt, [1152:1280)=u.
// Chunked: msg_c is a CH-row chunk, src_c the matching slice of src.
// ---------------------------------------------------------------------------
__global__ __launch_bounds__(256) void pass1_kernel(
    const float* __restrict__ msg_c, const int* __restrict__ src_c,
    float* __restrict__ cnt, float* __restrict__ h)
{
  const int e = blockIdx.x;
  const int f = threadIdx.x;
  const int s = src_c[e];
  const float v = msg_c[(size_t)e * FM + f];
  float* base = h + (size_t)s * FM2;
  atomicAdd(base + 128 + f, v);       // sum x  -> mean slot
  atomicAdd(base + 384 + f, v * v);   // sum x2 -> std slot
  if (f == 0) atomicAdd(&cnt[s], 1.0f);
}

// mean slot <- mean; std slot <- var = leaky(m2 - mean^2, 0.01)
__global__ __launch_bounds__(256) void fin1_kernel(
    const float* __restrict__ cnt, float* __restrict__ h)
{
  const int i = blockIdx.x * 256 + threadIdx.x;   // S*FM
  const int s = i >> 8, f = i & 255;
  float* base = h + (size_t)s * FM2;
  const float denom = fmaxf(cnt[s], 1.0f);
  const float mean = base[128 + f] / denom;
  const float m2   = base[384 + f] / denom;
  float var = m2 - mean * mean;
  var = var > 0.0f ? var : 0.01f * var;
  base[128 + f] = mean;
  base[384 + f] = var;
}

__global__ __launch_bounds__(256) void pass2_kernel(
    const float* __restrict__ msg_c, const int* __restrict__ src_c,
    float* __restrict__ h)
{
  const int e = blockIdx.x;
  const int f = threadIdx.x;
  const int s = src_c[e];
  float* base = h + (size_t)s * FM2;
  const float d = msg_c[(size_t)e * FM + f] - base[128 + f];
  const float d3 = d * d * d;
  atomicAdd(base + 640 + f, d3);
  atomicAdd(base + 896 + f, d3 * d);
}

__global__ __launch_bounds__(256) void build_h_stats_kernel(
    const float* __restrict__ cnt, float* __restrict__ h)
{
  const int i = blockIdx.x * 256 + threadIdx.x;   // S*FM
  const int s = i >> 8, f = i & 255;
  float* base = h + (size_t)s * FM2;
  const float denom = fmaxf(cnt[s], 1.0f);
  const float mean = base[128 + f];
  const float var  = base[384 + f];
  const float sd3  = base[640 + f];
  const float sd4  = base[896 + f];
  float skew = 0.0f, kurt = 0.0f;
  const float v1e = var + 1e-6f;
  if (v1e > 0.0f) {        // else ref sqrt(neg)=NaN -> nan_to_num -> 0
    const float stdv = sqrtf(v1e);
    const float st3  = stdv * stdv * stdv;
    skew = (sd3 / denom) / st3;
    kurt = (sd4 / denom) / (st3 * stdv);
  }
  const float var2 = n2n(var);
  const float std2 = sqrtf(fmaxf(var2 + 1e-6f, 0.0f));
  base[128 + f] = n2n(mean);
  base[384 + f] = std2;
  base[640 + f] = n2n(skew);
  base[896 + f] = n2n(kurt);
}

__global__ __launch_bounds__(256) void build_h_xu_kernel(
    const float* __restrict__ x_s, const float* __restrict__ u,
    float* __restrict__ h)
{
  const int i = blockIdx.x * 256 + threadIdx.x;   // S*FD
  const int s = i >> 7, f = i & 127;
  float* base = h + (size_t)s * FM2;
  base[f] = x_s[i];
  base[1152 + f] = u[f];
}

// BatchNorm
__global__ __launch_bounds__(256) void bn_sum_kernel(
    const float* __restrict__ y, float* __restrict__ bn)
{
  __shared__ float ls[256], lq[256];
  const int t = threadIdx.x;
  const int col = t & 127, half = t >> 7;
  const int rend = min(S_N, (int)blockIdx.x * 256 + 256);
  float sm = 0.f, sq = 0.f;
  for (int r = blockIdx.x * 256 + half; r < rend; r += 2) {
    const float v = y[(size_t)r * FD + col];
    sm += v; sq += v * v;
  }
  ls[t] = sm; lq[t] = sq;
  __syncthreads();
  if (t < 128) {
    atomicAdd(&bn[col],       ls[t] + ls[t + 128]);
    atomicAdd(&bn[128 + col], lq[t] + lq[t + 128]);
  }
}

__global__ __launch_bounds__(256) void bn_norm_kernel(
    const float* __restrict__ y, const float* __restrict__ bn,
    const float* __restrict__ gamma, const float* __restrict__ beta,
    float* __restrict__ out)
{
  const int i = blockIdx.x * 256 + threadIdx.x;   // S*FD
  const int f = i & 127;
  const float mu  = bn[f] * (1.0f / S_N);
  const float var = bn[128 + f] * (1.0f / S_N) - mu * mu;
  const float inv = 1.0f / sqrtf(var + 1e-5f);
  out[i] = (y[i] - mu) * inv * gamma[f] + beta[f];
}

// ---------------------------------------------------------------------------
// Workspace layout, total ~418 MB (proven-safe extent < 481 MB):
//   OFF_H    = 0           h f32 [S,1280], stat slots embedded (zeroed)
//   OFF_CNT  = 256,000,000 cnt f32 [S]
//   OFF_BN   = 256,200,192 bn f32 [256]
//   OFF_FLG  = 256,201,216 flags int[2]
//   OFF_Y    = 256,201,728 y f32 [S,128]
//   OFF_G    = 281,801,728 g chunk f32 [RCH,1280]
//   OFF_MSGC = 333,001,728 msg chunk f32 [CH,256]
//   OFF_H1C  = 373,961,728 h1 chunk f32 [CH,256]
//   OFF_SRC  = 414,921,728 src32 int [E]
//   OFF_TGT  = 416,521,728 tgt32 int [E]   (end 418,121,728)
// ---------------------------------------------------------------------------
#define OFF_H    0ull
#define OFF_CNT  256000000ull
#define OFF_BN   256200192ull
#define OFF_FLG  256201216ull
#define OFF_Y    256201728ull
#define OFF_G    281801728ull
#define OFF_MSGC 333001728ull
#define OFF_H1C  373961728ull
#define OFF_SRC  414921728ull
#define OFF_TGT  416521728ull

extern "C" void kernel_launch(void* const* d_in, const int* in_sizes, int n_in,
                              void* d_out, int out_size, void* d_ws, size_t ws_size,
                              hipStream_t stream)
{
  const float* x_s  = (const float*)d_in[0];
  const float* x_t  = (const float*)d_in[1];
  const float* ea   = (const float*)d_in[2];
  const float* u    = (const float*)d_in[3];
  const float* W1a  = (const float*)d_in[4];
  const float* b1a  = (const float*)d_in[5];
  const float* W1b  = (const float*)d_in[6];
  const float* b1b  = (const float*)d_in[7];
  const float* W2a  = (const float*)d_in[8];
  const float* b2a  = (const float*)d_in[9];
  const float* W2b  = (const float*)d_in[10];
  const float* b2b  = (const float*)d_in[11];
  const float* gam  = (const float*)d_in[12];
  const float* bet  = (const float*)d_in[13];

  char* ws = (char*)d_ws;
  float* h    = (float*)(ws + OFF_H);
  float* cnt  = (float*)(ws + OFF_CNT);
  float* bn   = (float*)(ws + OFF_BN);
  int*   flags= (int*)(ws + OFF_FLG);
  float* y    = (float*)(ws + OFF_Y);
  float* g    = (float*)(ws + OFF_G);
  float* msgc = (float*)(ws + OFF_MSGC);
  float* h1c  = (float*)(ws + OFF_H1C);
  int*   src32= (int*)(ws + OFF_SRC);
  int*   tgt32= (int*)(ws + OFF_TGT);

  // zero h (stat slots) + cnt + bn; probe + normalize indices
  hipMemsetAsync(ws, 0, OFF_FLG, stream);
  probe_kernel<<<1, 64, 0, stream>>>(d_in[14], flags);
  idx_kernel<<<(E_N + 255) / 256, 256, 0, stream>>>(d_in[14], src32, tgt32, flags);

  // ---- pass 1: MLP1 per chunk -> sum/sumsq atomics (msg not materialized)
  for (int c = 0; c < NC; ++c) {
    const size_t r0 = (size_t)c * CH;
    gemm1_f32_kernel<<<dim3(CH / 64, FM / 64), 256, 0, stream>>>(
        x_t, ea + r0 * FD, tgt32 + r0, W1a, b1a, h1c);
    gemm_f32_kernel<false><<<dim3(CH / 64, FM / 64), 256, 0, stream>>>(
        h1c, W1b, b1b, msgc, CH, FM, FM);
    pass1_kernel<<<CH, 256, 0, stream>>>(msgc, src32 + r0, cnt, h);
  }
  fin1_kernel<<<(S_N * FM) / 256, 256, 0, stream>>>(cnt, h);

  // ---- pass 2: recompute MLP1 per chunk -> d3/d4 atomics
  for (int c = 0; c < NC; ++c) {
    const size_t r0 = (size_t)c * CH;
    gemm1_f32_kernel<<<dim3(CH / 64, FM / 64), 256, 0, stream>>>(
        x_t, ea + r0 * FD, tgt32 + r0, W1a, b1a, h1c);
    gemm_f32_kernel<false><<<dim3(CH / 64, FM / 64), 256, 0, stream>>>(
        h1c, W1b, b1b, msgc, CH, FM, FM);
    pass2_kernel<<<CH, 256, 0, stream>>>(msgc, src32 + r0, h);
  }
  build_h_stats_kernel<<<(S_N * FM) / 256, 256, 0, stream>>>(cnt, h);
  build_h_xu_kernel<<<(S_N * FD) / 256, 256, 0, stream>>>(x_s, u, h);

  // ---- MLP2, row-chunked: h -> g -> y
  for (int c = 0; c < S_N / RCH; ++c) {
    const size_t r0 = (size_t)c * RCH;
    gemm_f32_kernel<true><<<dim3((RCH + 63) / 64, FM2 / 64), 256, 0, stream>>>(
        h + r0 * FM2, W2a, b2a, g, RCH, FM2, FM2);
    gemm_f32_kernel<false><<<dim3((RCH + 63) / 64, FD / 64), 256, 0, stream>>>(
        g, W2b, b2b, y + r0 * FD, RCH, FD, FM2);
  }

  // ---- BatchNorm -> d_out (f32)
  bn_sum_kernel<<<(S_N + 255) / 256, 256, 0, stream>>>(y, bn);
  bn_norm_kernel<<<(S_N * FD) / 256, 256, 0, stream>>>(y, bn, gam, bet, (float*)d_out);
}